// Round 1
// baseline (347.699 us; speedup 1.0000x reference)
//
#include <hip/hip_runtime.h>
#include <stdint.h>

// Problem geometry (fixed per reference)
#define BATCH 32
#define HGT   128
#define WID   128
#define NCLS  80
#define NPB   (HGT*WID*NCLS)   // 1,310,720 scores per batch
#define HW    (HGT*WID)        // 16,384 spatial locations
#define TOPK  100
#define NBINS 4096             // top 12 bits of sortable key
#define CAP   2048             // candidate cap per batch (expect ~120-350)
#define SORT_N 2048

// Monotone map: float bits -> uint32 such that key order == float order
__device__ __forceinline__ uint32_t f2key(uint32_t u) {
    return (u & 0x80000000u) ? ~u : (u | 0x80000000u);
}

// ---------------- Pass 1: per-batch 4096-bin histogram ----------------
__global__ void hist_kernel(const float* __restrict__ cls, uint32_t* __restrict__ hist) {
    __shared__ uint32_t lh[NBINS];
    const int b = blockIdx.y;
    for (int i = threadIdx.x; i < NBINS; i += blockDim.x) lh[i] = 0;
    __syncthreads();

    const uint4* p = (const uint4*)(cls + (size_t)b * NPB);
    const int nvec = NPB / 4;  // 327,680
    for (int i = blockIdx.x * blockDim.x + threadIdx.x; i < nvec;
         i += gridDim.x * blockDim.x) {
        uint4 v = p[i];
        atomicAdd(&lh[f2key(v.x) >> 20], 1u);
        atomicAdd(&lh[f2key(v.y) >> 20], 1u);
        atomicAdd(&lh[f2key(v.z) >> 20], 1u);
        atomicAdd(&lh[f2key(v.w) >> 20], 1u);
    }
    __syncthreads();

    uint32_t* gh = hist + (size_t)b * NBINS;
    for (int i = threadIdx.x; i < NBINS; i += blockDim.x) {
        uint32_t c = lh[i];
        if (c) atomicAdd(&gh[i], c);
    }
}

// ---------------- Pass 2: find per-batch threshold bin ----------------
// thresh[b] = lower-bound key of the highest bin whose suffix count >= TOPK
__global__ void thresh_kernel(const uint32_t* __restrict__ hist,
                              uint32_t* __restrict__ thresh) {
    const int b = blockIdx.x;
    const uint32_t* gh = hist + (size_t)b * NBINS;
    __shared__ uint32_t csum[256];
    __shared__ uint32_t suffix[256];
    __shared__ int bestBin;
    const int t = threadIdx.x;          // 256 threads, 16 bins each

    uint32_t local[16];
    uint32_t s = 0;
    #pragma unroll
    for (int i = 0; i < 16; i++) { local[i] = gh[t * 16 + i]; s += local[i]; }
    csum[t] = s;
    if (t == 0) bestBin = 0;
    __syncthreads();

    if (t == 0) {                        // exclusive suffix sums over chunks
        uint32_t run = 0;
        for (int i = 255; i >= 0; i--) { suffix[i] = run; run += csum[i]; }
    }
    __syncthreads();

    uint32_t run = suffix[t];
    int best = -1;
    #pragma unroll
    for (int i = 15; i >= 0; i--) {      // walk chunk from its top bin down
        run += local[i];
        if (run >= TOPK) { best = t * 16 + i; break; }
    }
    if (best >= 0) atomicMax(&bestBin, best);
    __syncthreads();
    if (t == 0) thresh[b] = ((uint32_t)bestBin) << 20;
}

// ---------------- Pass 3: compact candidates >= threshold ----------------
__global__ void filter_kernel(const float* __restrict__ cls,
                              const uint32_t* __restrict__ thresh,
                              uint32_t* __restrict__ counts,
                              uint64_t* __restrict__ cand) {
    const int b = blockIdx.y;
    const uint32_t th = thresh[b];
    const uint4* p = (const uint4*)(cls + (size_t)b * NPB);
    uint64_t* cb = cand + (size_t)b * CAP;
    const int nvec = NPB / 4;
    for (int i = blockIdx.x * blockDim.x + threadIdx.x; i < nvec;
         i += gridDim.x * blockDim.x) {
        uint4 v = p[i];
        const uint32_t base = (uint32_t)i * 4u;
        uint32_t ks[4] = { f2key(v.x), f2key(v.y), f2key(v.z), f2key(v.w) };
        #pragma unroll
        for (int j = 0; j < 4; j++) {
            if (ks[j] >= th) {
                uint32_t pos = atomicAdd(&counts[b], 1u);
                if (pos < CAP)
                    cb[pos] = ((uint64_t)ks[j] << 32) |
                              (uint64_t)(0xFFFFFFFFu - (base + j));
            }
        }
    }
}

// ---------------- Pass 4: sort candidates, decode, write output ----------------
__global__ void select_kernel(const uint64_t* __restrict__ cand,
                              const uint32_t* __restrict__ counts,
                              const float* __restrict__ loc,
                              float* __restrict__ out) {
    const int b = blockIdx.x;
    __shared__ uint64_t s[SORT_N];
    uint32_t n = counts[b];
    if (n > CAP) n = CAP;
    const uint64_t* cb = cand + (size_t)b * CAP;
    for (int i = threadIdx.x; i < SORT_N; i += blockDim.x)
        s[i] = (i < (int)n) ? cb[i] : 0ull;   // 0 sorts to the bottom
    __syncthreads();

    // bitonic sort, descending overall
    for (int k2 = 2; k2 <= SORT_N; k2 <<= 1) {
        for (int j = k2 >> 1; j > 0; j >>= 1) {
            for (int i = threadIdx.x; i < SORT_N; i += blockDim.x) {
                int ixj = i ^ j;
                if (ixj > i) {
                    uint64_t a = s[i], c = s[ixj];
                    bool desc = ((i & k2) == 0);
                    bool doSwap = desc ? (a < c) : (a > c);
                    if (doSwap) { s[i] = c; s[ixj] = a; }
                }
            }
            __syncthreads();
        }
    }

    for (int i = threadIdx.x; i < TOPK; i += blockDim.x) {
        uint64_t e = s[i];
        uint32_t key = (uint32_t)(e >> 32);
        uint32_t idx = 0xFFFFFFFFu - (uint32_t)(e & 0xFFFFFFFFu);
        uint32_t u   = (key & 0x80000000u) ? (key ^ 0x80000000u) : ~key;
        float score  = __uint_as_float(u);
        uint32_t cid = idx % NCLS;
        uint32_t sp  = idx / NCLS;
        float4 l = *(const float4*)(loc + ((size_t)b * HW + sp) * 4);
        float* o = out + ((size_t)b * TOPK + i) * 6;
        o[0] = l.x; o[1] = l.y; o[2] = l.z; o[3] = l.w;
        o[4] = score;
        o[5] = (float)cid;
    }
}

extern "C" void kernel_launch(void* const* d_in, const int* in_sizes, int n_in,
                              void* d_out, int out_size, void* d_ws, size_t ws_size,
                              hipStream_t stream) {
    const float* cls = (const float*)d_in[0];
    const float* loc = (const float*)d_in[1];
    float* out = (float*)d_out;

    // Workspace layout (total ~1.05 MB):
    //   [0, 512K)          cand  : 32 * 2048 * u64
    //   [512K, 1024K)      hist  : 32 * 4096 * u32
    //   [1024K, +128)      thresh: 32 * u32
    //   [1024K+128, +256)  counts: 32 * u32
    uint8_t* ws = (uint8_t*)d_ws;
    uint64_t* cand   = (uint64_t*)ws;
    uint32_t* hist   = (uint32_t*)(ws + (size_t)BATCH * CAP * 8);
    uint32_t* thresh = (uint32_t*)(ws + (size_t)BATCH * CAP * 8 + (size_t)BATCH * NBINS * 4);
    uint32_t* counts = thresh + BATCH;

    // zero hist + thresh + counts (ws is poisoned 0xAA before every call)
    hipMemsetAsync(hist, 0, (size_t)BATCH * NBINS * 4 + 2 * BATCH * 4, stream);

    hist_kernel  <<<dim3(80, BATCH), 256, 0, stream>>>(cls, hist);
    thresh_kernel<<<BATCH, 256, 0, stream>>>(hist, thresh);
    filter_kernel<<<dim3(80, BATCH), 256, 0, stream>>>(cls, thresh, counts, cand);
    select_kernel<<<BATCH, 256, 0, stream>>>(cand, counts, loc, out);
}